// Round 17
// baseline (238.876 us; speedup 1.0000x reference)
//
#include <hip/hip_runtime.h>

// Problem constants (fixed by setup_inputs)
constexpr int Bn = 128, Cn = 3, Sn = 256;
constexpr int HWn = Sn * Sn;          // 65536
constexpr int NPLANE = Bn * Cn;       // 384
constexpr float DTf = 0.05f;
constexpr float EPSf = 1e-6f;
constexpr float MAXCf = 1.0f;

// ws float layout:
//   [128..10111]    tapx [3 c][13 d][256 i]   (zero for OOB sources)
//   [10368..20351]  tapy [3 c][13 d][256 i]   (dg^3 folded in; zero for OOB)
//   [20480..]       tmp  [384][256][256]  (x-convolved field), if ws permits
#define WS_TAPX 128
#define WS_TAPY 10368
#define WS_TMP  20480

// ---- build composed banded operator taps (+ fused spatial mean) ----------
__global__ void build_taps(const float* __restrict__ alpha_base,
                           const float* __restrict__ beta_base,
                           const float* __restrict__ aspat,
                           const float* __restrict__ bspat,
                           const float* __restrict__ coupling,
                           float* __restrict__ ws) {
  __shared__ double sm[256];
  __shared__ float cp3[3][288], di3[3][288];   // padded: idx = i+16, zeros outside [0,255]
  __shared__ float s_mean;
  const int dirc = blockIdx.x, dir = dirc / 3, c = dirc % 3;
  const int j = threadIdx.x;
  {
    const float4* p = (const float4*)((dir == 0 ? aspat : bspat) + c * HWn) + j;
    double acc = 0.0;
#pragma unroll
    for (int k2 = 0; k2 < 64; ++k2) {
      float4 v = p[k2 * 256];
      acc += (double)v.x + (double)v.y + (double)v.z + (double)v.w;
    }
    sm[j] = acc;
    __syncthreads();
    for (int s2 = 128; s2 > 0; s2 >>= 1) {
      if (j < s2) sm[j] += sm[j + s2];
      __syncthreads();
    }
    if (j == 0) s_mean = (float)(sm[0] * (1.0 / 65536.0));
    __syncthreads();
  }
  if (j < 3) {
    const int k = j;
    const float base = (dir == 0) ? alpha_base[c] : beta_base[c];
    const float coef = fminf(fmaxf(base + s_mean * ((float)k * DTf), EPSf), MAXCf);
    const float r = coef * (DTf * 0.5f);       // DX = 1
    for (int p = 0; p < 16; ++p) {
      cp3[k][p] = 0.f; di3[k][p] = 0.f;
      cp3[k][272 + p] = 0.f; di3[k][272 + p] = 0.f;
    }
    float b0 = 1.f + r + EPSf;                 // reference: b[0] + eps
    float cq = -r / b0, dq = 1.f / b0;
    cp3[k][16] = cq; di3[k][16] = dq;
    for (int i = 1; i < 256; ++i) {
      float b = (i == 255) ? (1.f + r) : (1.f + 2.f * r);
      float den = fmaxf(b + r * cq, EPSf);     // b - a*cp_prev, a = -r
      cq = -r / den; dq = 1.f / den;
      cp3[k][16 + i] = cq; di3[k][16 + i] = dq;
    }
  }
  float* tb = ws + ((dir == 0) ? WS_TAPX : WS_TAPY) + c * 13 * 256;
#pragma unroll
  for (int d = 0; d < 13; ++d) tb[d * 256 + j] = 0.f;   // OOB-source taps stay 0
  __syncthreads();

  float z[33];                                  // o = 0..32 <-> row i = j-16+o
#pragma unroll
  for (int o = 0; o < 33; ++o) z[o] = (o == 16) ? 1.f : 0.f;
#pragma unroll
  for (int k = 0; k < 3; ++k) {
    float dp = 0.f;
#pragma unroll
    for (int o = 0; o < 33; ++o) {              // forward: dp in place
      const int p = j + o;
      dp = fmaf(-cp3[k][p], dp, z[o] * di3[k][p]);
      z[o] = dp;
    }
    float x = 0.f;
#pragma unroll
    for (int o = 32; o >= 0; --o) {             // backward: x = dp - cp*x_next
      const int p = j + o;
      x = fmaf(-cp3[k][p], x, z[o]);
      z[o] = x;
    }
  }
  float scale = 1.f;
  if (dir == 1) {
    float dgc = coupling[c * 3 + c];
    scale = dgc * dgc * dgc;                    // diag applied after each step
  }
#pragma unroll
  for (int o = -6; o <= 6; ++o) {
    const int i = j + o;                        // output row; d = 6 - o
    if ((unsigned)i < 256u) tb[(6 - o) * 256 + i] = z[o + 16] * scale;
  }
}

// ---- streaming kernel 1: tmp = u * X^T (x-conv along rows) ---------------
// Wave = one row; lane l owns quad l (cols 4l..4l+3). Loads: quads l-2..l+2
// (5 instructions, each 64x16B contiguous = 1KB dense). Interior taps via
// block-uniform s_load; edge lanes (<2, >=62) recompute boundary cols
// 0-5/250-255 with true per-col taps (zero taps kill clamped-garbage and
// duplicated-quad values — index-verified). Store: own quad, 1KB dense.
__global__ __launch_bounds__(256, 8) void convx(
    const float* __restrict__ src, float* __restrict__ tmp,
    const float* __restrict__ ws) {
  const int t = threadIdx.x;
  const int rid = blockIdx.x * 4 + (t >> 6);   // wave -> row; block = 4 rows
  const int l = t & 63;                        // lane -> quad
  const int c = (blockIdx.x >> 6) % 3;         // block-uniform channel
  const float* tpx = ws + WS_TAPX + c * 3328;
  float tx[13];
#pragma unroll
  for (int d = 0; d < 13; ++d) tx[d] = tpx[d * 256 + 128];  // uniform -> s_load
  const float* row = src + (size_t)rid * 256;
  float in_[20];                               // cols [4l-8, 4l+12), quads clamped
#pragma unroll
  for (int m = 0; m < 5; ++m) {
    int q = l - 2 + m;
    q = q < 0 ? 0 : (q > 63 ? 63 : q);
    *(float4*)&in_[4 * m] = *(const float4*)(row + 4 * q);
  }
  float acc[4];
#pragma unroll
  for (int e = 0; e < 4; ++e) acc[e] = tx[0] * in_[e + 2];
#pragma unroll
  for (int d = 1; d < 13; ++d)
#pragma unroll
    for (int e = 0; e < 4; ++e) acc[e] = fmaf(tx[d], in_[e + 2 + d], acc[e]);
  if (l < 2) {                                 // true taps for cols 0..5
#pragma unroll
    for (int e = 0; e < 4; ++e) {
      const int col = 4 * l + e;
      if (col < 6) {
        float a = 0.f;
#pragma unroll
        for (int d = 0; d < 13; ++d) a = fmaf(tpx[d * 256 + col], in_[e + 2 + d], a);
        acc[e] = a;
      }
    }
  } else if (l >= 62) {                        // true taps for cols 250..255
#pragma unroll
    for (int e = 0; e < 4; ++e) {
      const int col = 4 * l + e;
      if (col >= 250) {
        float a = 0.f;
#pragma unroll
        for (int d = 0; d < 13; ++d) a = fmaf(tpx[d * 256 + col], in_[e + 2 + d], a);
        acc[e] = a;
      }
    }
  }
  *(float4*)(tmp + (size_t)rid * 256 + 4 * l) =
      make_float4(acc[0], acc[1], acc[2], acc[3]);
}

// ---- streaming kernel 2: out = Y * tmp (y-conv along columns) ------------
// No LDS, no barriers. Thread = (col-pair, 32-row chunk): rolling float2
// win[13]; row taps wave-uniform s_load; clamped row reads pair with zero
// taps. tmp is L3-resident (written by convx just before). 512B-dense ops.
__global__ __launch_bounds__(256, 8) void convy(
    const float* __restrict__ tmp, float* __restrict__ dst,
    const float* __restrict__ ws) {
  const int t = threadIdx.x;
  const int plane = blockIdx.x >> 2;
  const int chunk = (blockIdx.x & 3) * 2 + (t >> 7);   // 0..7, wave-uniform
  const int pair = t & 127;
  const int c = plane % 3;
  const float* tpy = ws + WS_TAPY + c * 3328;
  const float* tp = tmp + (size_t)plane * HWn + 2 * pair;
  float* dp = dst + (size_t)plane * HWn + 2 * pair;
  const int g0 = 32 * chunk;
  float2 win[13];                              // rows g-6 .. g+6 of this pair
#pragma unroll
  for (int m = 0; m < 12; ++m) {
    int gg = g0 - 6 + m;
    gg = gg < 0 ? 0 : gg;                      // clamped read x zero tap
    win[m] = *(const float2*)(tp + (size_t)gg * 256);
  }
#pragma unroll
  for (int rr = 0; rr < 32; ++rr) {
    const int g = g0 + rr;
    {
      int gg = g + 6;
      gg = gg > 255 ? 255 : gg;
      win[12] = *(const float2*)(tp + (size_t)gg * 256);
    }
    const int gu = __builtin_amdgcn_readfirstlane(g);
    float ox, oy;
    {
      const float ty = tpy[gu];                // wave-uniform -> s_load
      ox = ty * win[0].x; oy = ty * win[0].y;
    }
#pragma unroll
    for (int d = 1; d < 13; ++d) {
      const float ty = tpy[d * 256 + gu];
      ox = fmaf(ty, win[d].x, ox);
      oy = fmaf(ty, win[d].y, oy);
    }
    *(float2*)(dp + (size_t)g * 256) = make_float2(ox, oy);
#pragma unroll
    for (int m = 0; m < 12; ++m) win[m] = win[m + 1];
  }
}

// ---- fallback (R13-proven fused kernel, used only if ws lacks tmp room) ---
__global__ __launch_bounds__(512, 4) void conv3(
    const float* __restrict__ src, float* __restrict__ dst,
    const float* __restrict__ ws) {
  __shared__ float vt[76 * 256];               // 77824 B
  const int t = threadIdx.x;
  const int logical = (blockIdx.x & 7) * 192 + (blockIdx.x >> 3);
  const int plane = logical >> 2;
  const int st = logical & 3;
  const int c = plane % 3;
  const int h0 = st * 64;
  const int a = (st == 0) ? 0 : (h0 - 6);
  const int b = (st == 3) ? 256 : (h0 + 70);
  const int Wv = b - a;
  const float* tpx = ws + WS_TAPX + c * 3328;
  const float* tpy = ws + WS_TAPY + c * 3328;
  float tx[13];
#pragma unroll
  for (int d = 0; d < 13; ++d) tx[d] = tpx[d * 256 + 128];
  const float* srcp = src + (size_t)plane * HWn;

  const int NU = 16 * Wv;
#pragma unroll
  for (int p = 0; p < 3; ++p) {
    const int u = t + 512 * p;
    if (u < NU) {
      const int s = u & 15, rl = u >> 4;
      const float* row = srcp + (size_t)(a + rl) * 256;
      float in_[32];
#pragma unroll
      for (int mq = 0; mq < 8; ++mq) {
        int cl = 16 * s - 8 + 4 * mq;
        cl = cl < 0 ? 0 : (cl > 252 ? 252 : cl);
        *(float4*)&in_[4 * mq] = *(const float4*)(row + cl);
      }
      float acc[16];
#pragma unroll
      for (int e = 0; e < 16; ++e) acc[e] = tx[0] * in_[e + 2];
#pragma unroll
      for (int d = 1; d < 13; ++d)
#pragma unroll
        for (int e = 0; e < 16; ++e) acc[e] = fmaf(tx[d], in_[e + 2 + d], acc[e]);
      if (s == 0) {
#pragma unroll
        for (int e = 0; e < 6; ++e) {
          float ac = 0.f;
#pragma unroll
          for (int d = 0; d < 13; ++d) ac = fmaf(tpx[d * 256 + e], in_[e + 2 + d], ac);
          acc[e] = ac;
        }
      } else if (s == 15) {
#pragma unroll
        for (int e = 10; e < 16; ++e) {
          float ac = 0.f;
#pragma unroll
          for (int d = 0; d < 13; ++d) ac = fmaf(tpx[d * 256 + 240 + e], in_[e + 2 + d], ac);
          acc[e] = ac;
        }
      }
      const int sw = rl & 7;
      float4* vr = (float4*)vt + rl * 64;
#pragma unroll
      for (int jj = 0; jj < 4; ++jj)
        vr[(4 * s + jj) ^ sw] =
            make_float4(acc[4 * jj], acc[4 * jj + 1], acc[4 * jj + 2], acc[4 * jj + 3]);
    }
  }
  __syncthreads();

  const int pr = t & 127, rc = t >> 7;
  const int jq = pr >> 1, jin = (pr & 1) * 2;
  const int g0 = h0 + 16 * rc;
  float2 win[13];
#pragma unroll
  for (int m = 0; m < 12; ++m) {
    int gg = g0 - 6 + m;
    gg = gg < a ? a : gg;
    const int rl = gg - a;
    win[m] = *(const float2*)(vt + rl * 256 + (((jq ^ (rl & 7)) << 2) | jin));
  }
  float* dstp = dst + (size_t)plane * HWn + 2 * pr;
#pragma unroll
  for (int rr = 0; rr < 16; ++rr) {
    const int g = g0 + rr;
    {
      int gg = g + 6;
      gg = gg > b - 1 ? b - 1 : gg;
      const int rl = gg - a;
      win[12] = *(const float2*)(vt + rl * 256 + (((jq ^ (rl & 7)) << 2) | jin));
    }
    const int gu = __builtin_amdgcn_readfirstlane(g);
    float ox, oy;
    {
      const float ty = tpy[gu];
      ox = ty * win[0].x; oy = ty * win[0].y;
    }
#pragma unroll
    for (int d = 1; d < 13; ++d) {
      const float ty = tpy[d * 256 + gu];
      ox = fmaf(ty, win[d].x, ox);
      oy = fmaf(ty, win[d].y, oy);
    }
    *(float2*)(dstp + (size_t)g * 256) = make_float2(ox, oy);
#pragma unroll
    for (int m = 0; m < 12; ++m) win[m] = win[m + 1];
  }
}

extern "C" void kernel_launch(void* const* d_in, const int* in_sizes, int n_in,
                              void* d_out, int out_size, void* d_ws, size_t ws_size,
                              hipStream_t stream) {
  const float* u = (const float*)d_in[0];
  const float* alpha_base = (const float*)d_in[1];
  const float* beta_base = (const float*)d_in[2];
  const float* alpha_spatial = (const float*)d_in[3];
  const float* beta_spatial = (const float*)d_in[4];
  const float* coupling = (const float*)d_in[5];
  float* out = (float*)d_out;
  float* ws = (float*)d_ws;

  build_taps<<<6, 256, 0, stream>>>(alpha_base, beta_base,
                                    alpha_spatial, beta_spatial, coupling, ws);
  const size_t need = (size_t)(WS_TMP + (size_t)NPLANE * HWn) * sizeof(float);
  if (ws_size >= need) {
    float* tmp = ws + WS_TMP;
    convx<<<NPLANE * 64, 256, 0, stream>>>(u, tmp, ws);
    convy<<<NPLANE * 4, 256, 0, stream>>>(tmp, out, ws);
  } else {
    conv3<<<NPLANE * 4, 512, 0, stream>>>(u, out, ws);
  }
}

// Round 18
// 186.965 us; speedup vs baseline: 1.2776x; 1.2776x over previous
//
#include <hip/hip_runtime.h>

// Problem constants (fixed by setup_inputs)
constexpr int Bn = 128, Cn = 3, Sn = 256;
constexpr int HWn = Sn * Sn;          // 65536
constexpr int NPLANE = Bn * Cn;       // 384
constexpr float DTf = 0.05f;
constexpr float EPSf = 1e-6f;
constexpr float MAXCf = 1.0f;

// ws float layout:
//   [128..10111]    tapx [3 c][13 d][256 i]   (zero for OOB sources)
//   [10368..20351]  tapy [3 c][13 d][256 i]   (dg^3 folded in; zero for OOB)
#define WS_TAPX 128
#define WS_TAPY 10368

// ---- build composed banded operator taps (+ fused spatial mean) ----------
// All T_k = I + r_k*L commute; composed X (resp Y) = product of the three
// x-dir (y-dir) tridiagonal inverses. Thread j applies the three EXACT
// reference Thomas solves (incl. b0+eps, denom clamp, x_n = dp_n) to basis
// vector e_j, keeping rows [j-16, j+16] in registers. Band +-6 tail ~3e-10.
__global__ void build_taps(const float* __restrict__ alpha_base,
                           const float* __restrict__ beta_base,
                           const float* __restrict__ aspat,
                           const float* __restrict__ bspat,
                           const float* __restrict__ coupling,
                           float* __restrict__ ws) {
  __shared__ double sm[256];
  __shared__ float cp3[3][288], di3[3][288];   // padded: idx = i+16, zeros outside [0,255]
  __shared__ float s_mean;
  const int dirc = blockIdx.x, dir = dirc / 3, c = dirc % 3;
  const int j = threadIdx.x;
  {
    const float4* p = (const float4*)((dir == 0 ? aspat : bspat) + c * HWn) + j;
    double acc = 0.0;
#pragma unroll
    for (int k2 = 0; k2 < 64; ++k2) {
      float4 v = p[k2 * 256];
      acc += (double)v.x + (double)v.y + (double)v.z + (double)v.w;
    }
    sm[j] = acc;
    __syncthreads();
    for (int s2 = 128; s2 > 0; s2 >>= 1) {
      if (j < s2) sm[j] += sm[j + s2];
      __syncthreads();
    }
    if (j == 0) s_mean = (float)(sm[0] * (1.0 / 65536.0));
    __syncthreads();
  }
  if (j < 3) {
    const int k = j;
    const float base = (dir == 0) ? alpha_base[c] : beta_base[c];
    const float coef = fminf(fmaxf(base + s_mean * ((float)k * DTf), EPSf), MAXCf);
    const float r = coef * (DTf * 0.5f);       // DX = 1
    for (int p = 0; p < 16; ++p) {
      cp3[k][p] = 0.f; di3[k][p] = 0.f;
      cp3[k][272 + p] = 0.f; di3[k][272 + p] = 0.f;
    }
    float b0 = 1.f + r + EPSf;                 // reference: b[0] + eps
    float cq = -r / b0, dq = 1.f / b0;
    cp3[k][16] = cq; di3[k][16] = dq;
    for (int i = 1; i < 256; ++i) {
      float b = (i == 255) ? (1.f + r) : (1.f + 2.f * r);
      float den = fmaxf(b + r * cq, EPSf);     // b - a*cp_prev, a = -r
      cq = -r / den; dq = 1.f / den;
      cp3[k][16 + i] = cq; di3[k][16 + i] = dq;
    }
  }
  float* tb = ws + ((dir == 0) ? WS_TAPX : WS_TAPY) + c * 13 * 256;
#pragma unroll
  for (int d = 0; d < 13; ++d) tb[d * 256 + j] = 0.f;   // OOB-source taps stay 0
  __syncthreads();

  float z[33];                                  // o = 0..32 <-> row i = j-16+o
#pragma unroll
  for (int o = 0; o < 33; ++o) z[o] = (o == 16) ? 1.f : 0.f;
#pragma unroll
  for (int k = 0; k < 3; ++k) {
    float dp = 0.f;
#pragma unroll
    for (int o = 0; o < 33; ++o) {              // forward: dp in place
      const int p = j + o;
      dp = fmaf(-cp3[k][p], dp, z[o] * di3[k][p]);
      z[o] = dp;
    }
    float x = 0.f;
#pragma unroll
    for (int o = 32; o >= 0; --o) {             // backward: x = dp - cp*x_next
      const int p = j + o;
      x = fmaf(-cp3[k][p], x, z[o]);
      z[o] = x;
    }
  }
  float scale = 1.f;
  if (dir == 1) {
    float dgc = coupling[c * 3 + c];
    scale = dgc * dgc * dgc;                    // diag applied after each step
  }
#pragma unroll
  for (int o = -6; o <= 6; ++o) {
    const int i = j + o;                        // output row; d = 6 - o
    if ((unsigned)i < 256u) tb[(6 - o) * 256 + i] = z[o + 16] * scale;
  }
}

// ---- fused one-pass kernel, 3-blocks/CU geometry -------------------------
// Block = (plane, 32-row stripe): 44-row x 256-col LDS tile (45056 B ->
// 3 blocks/CU at (512,6); 24 waves/CU). 8 stripes/plane -> 3072 blocks =
// 4 rounds/CU: rounds + 3 resident blocks give phase diversity so DMA of
// one block overlaps compute of others (R13/R14's 2-block lockstep fix).
// LDS skew: quad q of a row lives at slot f(q) = q ^ (q>>3) (involution).
// DMA: lane l -> slot l, source quad f(l) (both-sides, rule #21).
// Stage 1 (barrier-free): wave wv owns rows {wv+8m} — DMAs them, per-wave
// vmcnt(0), x-convs lane-per-quad in place (wave-lockstep covers the +-2
// quad halo reads). Interior taps via block-uniform s_load; edge lanes
// recompute cols 0-5/250-255 with true per-col taps (zero taps kill
// clamped-garbage — numerically proven R13-R17, absmax 3.8e-6).
// ONE barrier. Stage 2: y-conv, col-pair units, rolling float2 win[13],
// row-uniform taps via s_load, dense float2 stores.
__global__ __launch_bounds__(512, 6) void conv3b(
    const float* __restrict__ src, float* __restrict__ dst,
    const float* __restrict__ ws) {
  __shared__ float vt[44 * 256];               // 45056 B
  const int t = threadIdx.x;
  // XCD-bijective swizzle: 3072 = 8*384; same-plane stripes -> same XCD
  // (adjacent stripes share halo rows -> L2 reuse).
  const int logical = (blockIdx.x & 7) * 384 + (blockIdx.x >> 3);
  const int plane = logical >> 3;
  const int st = logical & 7;
  const int c = plane % 3;
  const int h0 = st * 32;                      // core rows [h0, h0+32)
  const int a = (st == 0) ? 0 : (h0 - 6);
  const int b = (st == 7) ? 256 : (h0 + 38);
  const int Wv = b - a;                        // 38 edges, 44 interior
  const float* tpx = ws + WS_TAPX + c * 3328;
  const float* tpy = ws + WS_TAPY + c * 3328;
  const float* srcp = src + (size_t)plane * HWn;

  const int wv = t >> 6, l = t & 63;
  const int fl = l ^ (l >> 3);                 // involution skew

  // ---- DMA own rows: wave wv -> rows {wv + 8m} (1KB dense per load) ----
#pragma unroll
  for (int m = 0; m < 6; ++m) {
    const int rl = wv + 8 * m;
    if (rl < Wv) {
      const float* gp = srcp + (size_t)(a + rl) * 256 + (fl << 2);
      __builtin_amdgcn_global_load_lds(
          (const __attribute__((address_space(1))) void*)gp,
          (__attribute__((address_space(3))) void*)(vt + rl * 256), 16, 0, 0);
    }
  }
  float tx[13];                                 // interior x-taps (uniform -> s_load)
#pragma unroll
  for (int d = 0; d < 13; ++d) tx[d] = tpx[d * 256 + 128];
  asm volatile("s_waitcnt vmcnt(0)" ::: "memory");   // own rows only
  __builtin_amdgcn_sched_barrier(0);

  // ---- stage 1: x-conv own rows in place (lane-per-quad) ----
#pragma unroll
  for (int m = 0; m < 6; ++m) {
    const int rl = wv + 8 * m;
    if (rl < Wv) {
      float* rowl = vt + rl * 256;
      float in_[20];                           // cols [4l-8, 4l+12), quads clamped
#pragma unroll
      for (int mm = 0; mm < 5; ++mm) {
        int q = l - 2 + mm;
        q = q < 0 ? 0 : (q > 63 ? 63 : q);
        const int sl = q ^ (q >> 3);
        *(float4*)&in_[4 * mm] = *(const float4*)(rowl + 4 * sl);
      }
      float acc[4];
#pragma unroll
      for (int e = 0; e < 4; ++e) acc[e] = tx[0] * in_[e + 2];
#pragma unroll
      for (int d = 1; d < 13; ++d)
#pragma unroll
        for (int e = 0; e < 4; ++e) acc[e] = fmaf(tx[d], in_[e + 2 + d], acc[e]);
      if (l < 2) {                             // true taps for cols 0..5
#pragma unroll
        for (int e = 0; e < 4; ++e) {
          const int col = 4 * l + e;
          if (col < 6) {
            float ac = 0.f;
#pragma unroll
            for (int d = 0; d < 13; ++d)
              ac = fmaf(tpx[d * 256 + col], in_[e + 2 + d], ac);
            acc[e] = ac;
          }
        }
      } else if (l >= 62) {                    // true taps for cols 250..255
#pragma unroll
        for (int e = 0; e < 4; ++e) {
          const int col = 4 * l + e;
          if (col >= 250) {
            float ac = 0.f;
#pragma unroll
            for (int d = 0; d < 13; ++d)
              ac = fmaf(tpx[d * 256 + col], in_[e + 2 + d], ac);
            acc[e] = ac;
          }
        }
      }
      *(float4*)(rowl + 4 * fl) =              // own quad l -> slot f(l)
          make_float4(acc[0], acc[1], acc[2], acc[3]);
    }
  }
  __syncthreads();                             // the ONE barrier

  // ---- stage 2: y-conv. unit = (col-pair pr, 8-row chunk ys) ----
  const int pr = t & 127, ys = t >> 7;         // ys wave-uniform
  const int jq = pr >> 1;
  const int wpos = ((jq ^ (jq >> 3)) << 2) | ((pr & 1) * 2);
  const int g0 = h0 + 8 * ys;
  float2 win[13];                              // rows g-6 .. g+6 of this pair
#pragma unroll
  for (int m = 0; m < 12; ++m) {
    int gg = g0 - 6 + m;
    gg = gg < a ? a : gg;                      // clamped read x zero tap
    win[m] = *(const float2*)(vt + (gg - a) * 256 + wpos);
  }
  float* dstp = dst + (size_t)plane * HWn + 2 * pr;
#pragma unroll
  for (int rr = 0; rr < 8; ++rr) {
    const int g = g0 + rr;
    {
      int gg = g + 6;
      gg = gg > b - 1 ? b - 1 : gg;
      win[12] = *(const float2*)(vt + (gg - a) * 256 + wpos);
    }
    const int gu = __builtin_amdgcn_readfirstlane(g);
    float ox, oy;
    {
      const float ty = tpy[gu];                // wave-uniform -> s_load
      ox = ty * win[0].x; oy = ty * win[0].y;
    }
#pragma unroll
    for (int d = 1; d < 13; ++d) {
      const float ty = tpy[d * 256 + gu];
      ox = fmaf(ty, win[d].x, ox);
      oy = fmaf(ty, win[d].y, oy);
    }
    *(float2*)(dstp + (size_t)g * 256) = make_float2(ox, oy);
#pragma unroll
    for (int m = 0; m < 12; ++m) win[m] = win[m + 1];
  }
}

extern "C" void kernel_launch(void* const* d_in, const int* in_sizes, int n_in,
                              void* d_out, int out_size, void* d_ws, size_t ws_size,
                              hipStream_t stream) {
  const float* u = (const float*)d_in[0];
  const float* alpha_base = (const float*)d_in[1];
  const float* beta_base = (const float*)d_in[2];
  const float* alpha_spatial = (const float*)d_in[3];
  const float* beta_spatial = (const float*)d_in[4];
  const float* coupling = (const float*)d_in[5];
  float* out = (float*)d_out;
  float* ws = (float*)d_ws;

  build_taps<<<6, 256, 0, stream>>>(alpha_base, beta_base,
                                    alpha_spatial, beta_spatial, coupling, ws);
  conv3b<<<NPLANE * 8, 512, 0, stream>>>(u, out, ws);
}

// Round 19
// 115.380 us; speedup vs baseline: 2.0703x; 1.6204x over previous
//
#include <hip/hip_runtime.h>

// Problem constants (fixed by setup_inputs)
constexpr int Bn = 128, Cn = 3, Sn = 256;
constexpr int HWn = Sn * Sn;          // 65536
constexpr int NPLANE = Bn * Cn;       // 384
constexpr float DTf = 0.05f;
constexpr float EPSf = 1e-6f;
constexpr float MAXCf = 1.0f;

// ws float layout:
//   [128..10111]    tapx [3 c][13 d][256 i]   (zero for OOB sources)
//   [10368..20351]  tapy [3 c][13 d][256 i]   (dg^3 folded in; zero for OOB)
#define WS_TAPX 128
#define WS_TAPY 10368

// ---- build composed banded operator taps (+ fused spatial mean) ----------
// All T_k = I + r_k*L commute; thread j applies the three EXACT reference
// Thomas solves to basis vector e_j (rows [j-16,j+16] in regs); band +-6.
__global__ void build_taps(const float* __restrict__ alpha_base,
                           const float* __restrict__ beta_base,
                           const float* __restrict__ aspat,
                           const float* __restrict__ bspat,
                           const float* __restrict__ coupling,
                           float* __restrict__ ws) {
  __shared__ double sm[256];
  __shared__ float cp3[3][288], di3[3][288];   // padded: idx = i+16, zeros outside [0,255]
  __shared__ float s_mean;
  const int dirc = blockIdx.x, dir = dirc / 3, c = dirc % 3;
  const int j = threadIdx.x;
  {
    const float4* p = (const float4*)((dir == 0 ? aspat : bspat) + c * HWn) + j;
    double acc = 0.0;
#pragma unroll
    for (int k2 = 0; k2 < 64; ++k2) {
      float4 v = p[k2 * 256];
      acc += (double)v.x + (double)v.y + (double)v.z + (double)v.w;
    }
    sm[j] = acc;
    __syncthreads();
    for (int s2 = 128; s2 > 0; s2 >>= 1) {
      if (j < s2) sm[j] += sm[j + s2];
      __syncthreads();
    }
    if (j == 0) s_mean = (float)(sm[0] * (1.0 / 65536.0));
    __syncthreads();
  }
  if (j < 3) {
    const int k = j;
    const float base = (dir == 0) ? alpha_base[c] : beta_base[c];
    const float coef = fminf(fmaxf(base + s_mean * ((float)k * DTf), EPSf), MAXCf);
    const float r = coef * (DTf * 0.5f);       // DX = 1
    for (int p = 0; p < 16; ++p) {
      cp3[k][p] = 0.f; di3[k][p] = 0.f;
      cp3[k][272 + p] = 0.f; di3[k][272 + p] = 0.f;
    }
    float b0 = 1.f + r + EPSf;                 // reference: b[0] + eps
    float cq = -r / b0, dq = 1.f / b0;
    cp3[k][16] = cq; di3[k][16] = dq;
    for (int i = 1; i < 256; ++i) {
      float b = (i == 255) ? (1.f + r) : (1.f + 2.f * r);
      float den = fmaxf(b + r * cq, EPSf);     // b - a*cp_prev, a = -r
      cq = -r / den; dq = 1.f / den;
      cp3[k][16 + i] = cq; di3[k][16 + i] = dq;
    }
  }
  float* tb = ws + ((dir == 0) ? WS_TAPX : WS_TAPY) + c * 13 * 256;
#pragma unroll
  for (int d = 0; d < 13; ++d) tb[d * 256 + j] = 0.f;   // OOB-source taps stay 0
  __syncthreads();

  float z[33];                                  // o = 0..32 <-> row i = j-16+o
#pragma unroll
  for (int o = 0; o < 33; ++o) z[o] = (o == 16) ? 1.f : 0.f;
#pragma unroll
  for (int k = 0; k < 3; ++k) {
    float dp = 0.f;
#pragma unroll
    for (int o = 0; o < 33; ++o) {              // forward: dp in place
      const int p = j + o;
      dp = fmaf(-cp3[k][p], dp, z[o] * di3[k][p]);
      z[o] = dp;
    }
    float x = 0.f;
#pragma unroll
    for (int o = 32; o >= 0; --o) {             // backward: x = dp - cp*x_next
      const int p = j + o;
      x = fmaf(-cp3[k][p], x, z[o]);
      z[o] = x;
    }
  }
  float scale = 1.f;
  if (dir == 1) {
    float dgc = coupling[c * 3 + c];
    scale = dgc * dgc * dgc;                    // diag applied after each step
  }
#pragma unroll
  for (int o = -6; o <= 6; ++o) {
    const int i = j + o;                        // output row; d = 6 - o
    if ((unsigned)i < 256u) tb[(6 - o) * 256 + i] = z[o + 16] * scale;
  }
}

// ---- hot kernel: persistent double-buffered stripe pipeline ---------------
// Block = (plane, half). 5 stripes x 26 core rows (last h=1 stripe: 22).
// Buffer = 38 rows x 256 (skewed: quad q at slot f(q)=q^(q>>3), involution;
// DMA lane l -> linear slot l with pre-skewed source quad f(l), rule #21).
// Per stripe: issue next-stripe DMA FIRST (issue-early), x-conv current
// in LDS (in-place; all units of a row in one wave), raw s_barrier with
// lgkmcnt(0) ONLY (no vmcnt drain -> next-stripe loads stay in flight,
// T3/T4), y-conv -> out, then counted vmcnt(13) (5 oldest = DMA loads
// retired; <=13 younger stores may remain) + barrier, swap buffers.
// LDS 77824 B, (512,4): proven 2 blocks/CU, VGPR~52-64 envelope.
__global__ __launch_bounds__(512, 4) void conv_pipe(
    const float* __restrict__ src, float* __restrict__ dst,
    const float* __restrict__ ws) {
  __shared__ float vt[2][38 * 256];            // 77824 B
  const int t = threadIdx.x;
  // XCD-bijective swizzle: 768 = 8*96
  const int logical = (blockIdx.x & 7) * 96 + (blockIdx.x >> 3);
  const int plane = logical >> 1;
  const int h = logical & 1;
  const int c = plane % 3;
  const float* tpx = ws + WS_TAPX + c * 3328;
  const float* tpy = ws + WS_TAPY + c * 3328;
  const float* srcp = src + (size_t)plane * HWn;
  float* dstp = dst + (size_t)plane * HWn;

  float tx[13];                                 // interior x-taps (uniform)
#pragma unroll
  for (int d = 0; d < 13; ++d) tx[d] = tpx[d * 256 + 128];

  const int wv = t >> 6, l = t & 63;
  const int fl = l ^ (l >> 3);                  // involution skew

  // ---- prologue: stage stripe 0 into buffer 0 ----
  {
    const int c0 = 130 * h;
    const int aa = (c0 - 6 < 0) ? 0 : (c0 - 6);
    const int W = ((c0 + 32 > 256) ? 256 : (c0 + 32)) - aa;
#pragma unroll
    for (int m = 0; m < 5; ++m) {
      int rl = wv + 8 * m;
      if (rl > W - 1) rl = W - 1;               // duplicate-benign clamp
      const float* gp = srcp + (size_t)(aa + rl) * 256 + (fl << 2);
      __builtin_amdgcn_global_load_lds(
          (const __attribute__((address_space(1))) void*)gp,
          (__attribute__((address_space(3))) void*)(&vt[0][0] + rl * 256), 16, 0, 0);
    }
  }
  asm volatile("s_waitcnt vmcnt(0)" ::: "memory");
  __builtin_amdgcn_s_barrier();
  __builtin_amdgcn_sched_barrier(0);

  for (int s = 0; s < 5; ++s) {
    const int cur = s & 1;
    // current stripe geometry
    const int c0 = 130 * h + 26 * s;
    const int c1 = (h == 1 && s == 4) ? 256 : (c0 + 26);
    const int aa = (c0 - 6 < 0) ? 0 : (c0 - 6);
    const int bb = (c0 + 32 > 256) ? 256 : (c0 + 32);
    const int W = bb - aa;
    float* vb = &vt[cur][0];

    // ---- issue next stripe's DMA into the other buffer (issue-early) ----
    if (s < 4) {
      const int nc0 = c0 + 26;
      const int naa = nc0 - 6;                  // >= 20, no low clamp needed
      const int nW = ((nc0 + 32 > 256) ? 256 : (nc0 + 32)) - naa;
      float* nb = &vt[cur ^ 1][0];
#pragma unroll
      for (int m = 0; m < 5; ++m) {
        int rl = wv + 8 * m;
        if (rl > nW - 1) rl = nW - 1;
        const float* gp = srcp + (size_t)(naa + rl) * 256 + (fl << 2);
        __builtin_amdgcn_global_load_lds(
            (const __attribute__((address_space(1))) void*)gp,
            (__attribute__((address_space(3))) void*)(nb + rl * 256), 16, 0, 0);
      }
    }

    // ---- x-conv current stripe, in place (units: 16-col seg x row) ----
    {
      const int NU = 16 * W;
#pragma unroll
      for (int p = 0; p < 2; ++p) {
        const int u = t + 512 * p;
        if (u < NU) {
          const int sg = u & 15, rl = u >> 4;
          float* rowl = vb + rl * 256;
          float in_[32];                        // cols [16sg-8, 16sg+24)
#pragma unroll
          for (int mm = 0; mm < 8; ++mm) {
            int q = 4 * sg - 2 + mm;
            q = q < 0 ? 0 : (q > 63 ? 63 : q);
            const int sl = q ^ (q >> 3);
            *(float4*)&in_[4 * mm] = *(const float4*)(rowl + 4 * sl);
          }
          float acc[16];
#pragma unroll
          for (int e = 0; e < 16; ++e) acc[e] = tx[0] * in_[e + 2];
#pragma unroll
          for (int d = 1; d < 13; ++d)
#pragma unroll
            for (int e = 0; e < 16; ++e) acc[e] = fmaf(tx[d], in_[e + 2 + d], acc[e]);
          if (sg == 0) {                        // true taps for cols 0..5
#pragma unroll
            for (int e = 0; e < 6; ++e) {
              float ac = 0.f;
#pragma unroll
              for (int d = 0; d < 13; ++d)
                ac = fmaf(tpx[d * 256 + e], in_[e + 2 + d], ac);
              acc[e] = ac;
            }
          } else if (sg == 15) {                // true taps for cols 250..255
#pragma unroll
            for (int e = 10; e < 16; ++e) {
              float ac = 0.f;
#pragma unroll
              for (int d = 0; d < 13; ++d)
                ac = fmaf(tpx[d * 256 + 240 + e], in_[e + 2 + d], ac);
              acc[e] = ac;
            }
          }
#pragma unroll
          for (int jj = 0; jj < 4; ++jj) {      // own quads -> skewed slots
            const int q = 4 * sg + jj;
            const int sl = q ^ (q >> 3);
            *(float4*)(rowl + 4 * sl) =
                make_float4(acc[4 * jj], acc[4 * jj + 1], acc[4 * jj + 2], acc[4 * jj + 3]);
          }
        }
      }
    }
    // barrier WITHOUT vmcnt drain: LDS writes visible, DMA stays in flight
    asm volatile("s_waitcnt lgkmcnt(0)" ::: "memory");
    __builtin_amdgcn_s_barrier();
    __builtin_amdgcn_sched_barrier(0);

    // ---- y-conv current stripe -> out (unit: col x 13-row chunk) ----
    {
      const int j = t & 255, rc2 = t >> 8;      // 2 chunks of 13 rows
      const int jq = j >> 2;
      const int wpos = ((jq ^ (jq >> 3)) << 2) | (j & 3);
      const int g0 = c0 + 13 * rc2;
      const int gend = (c1 < g0 + 13) ? c1 : (g0 + 13);
      float win[13];
#pragma unroll
      for (int m = 0; m < 12; ++m) {
        int gg = g0 - 6 + m;
        gg = gg < aa ? aa : gg;                 // clamped read x zero tap
        win[m] = vb[(gg - aa) * 256 + wpos];
      }
      float* dcol = dstp + j;
#pragma unroll
      for (int rr = 0; rr < 13; ++rr) {
        const int g = g0 + rr;
        if (g < gend) {                         // uniform guard
          int gg = g + 6;
          gg = gg > bb - 1 ? bb - 1 : gg;
          win[12] = vb[(gg - aa) * 256 + wpos];
          const int gu = __builtin_amdgcn_readfirstlane(g);
          float o = tpy[gu] * win[0];
#pragma unroll
          for (int d = 1; d < 13; ++d) o = fmaf(tpy[d * 256 + gu], win[d], o);
          dcol[(size_t)g * 256] = o;
#pragma unroll
          for (int m = 0; m < 12; ++m) win[m] = win[m + 1];
        }
      }
    }
    // counted wait: 5 oldest (next-stripe DMA) retired; stores may remain.
    asm volatile("s_waitcnt vmcnt(13) lgkmcnt(0)" ::: "memory");
    __builtin_amdgcn_s_barrier();
    __builtin_amdgcn_sched_barrier(0);
  }
}

extern "C" void kernel_launch(void* const* d_in, const int* in_sizes, int n_in,
                              void* d_out, int out_size, void* d_ws, size_t ws_size,
                              hipStream_t stream) {
  const float* u = (const float*)d_in[0];
  const float* alpha_base = (const float*)d_in[1];
  const float* beta_base = (const float*)d_in[2];
  const float* alpha_spatial = (const float*)d_in[3];
  const float* beta_spatial = (const float*)d_in[4];
  const float* coupling = (const float*)d_in[5];
  float* out = (float*)d_out;
  float* ws = (float*)d_ws;

  build_taps<<<6, 256, 0, stream>>>(alpha_base, beta_base,
                                    alpha_spatial, beta_spatial, coupling, ws);
  conv_pipe<<<NPLANE * 2, 512, 0, stream>>>(u, out, ws);
}

// Round 20
// 105.025 us; speedup vs baseline: 2.2745x; 1.0986x over previous
//
#include <hip/hip_runtime.h>

// Problem constants (fixed by setup_inputs)
constexpr int Bn = 128, Cn = 3, Sn = 256;
constexpr int HWn = Sn * Sn;          // 65536
constexpr int NPLANE = Bn * Cn;       // 384
constexpr float DTf = 0.05f;
constexpr float EPSf = 1e-6f;
constexpr float MAXCf = 1.0f;

// ws float layout (band +-2 = 5 taps):
//   [128..3967]     tapx [3 c][5 d][256 i]   (zero for OOB sources)
//   [4096..7935]    tapy [3 c][5 d][256 i]   (dg^3 folded in; zero for OOB)
#define WS_TAPX 128
#define WS_TAPY 4096

// ---- build composed banded operator taps (+ fused spatial mean) ----------
// All T_k = I + r_k*L commute; thread j applies the three EXACT reference
// Thomas solves to basis vector e_j (rows [j-16,j+16] in regs).
// BAND +-2: tap(d) ~ (3r)^d with 3r~0.023 -> tap(3)~1.2e-5; dropped-tap
// output error <= tap(3)*max|u|*dg^3 ~ 2e-8 << 2.15e-5 threshold.
__global__ void build_taps(const float* __restrict__ alpha_base,
                           const float* __restrict__ beta_base,
                           const float* __restrict__ aspat,
                           const float* __restrict__ bspat,
                           const float* __restrict__ coupling,
                           float* __restrict__ ws) {
  __shared__ double sm[256];
  __shared__ float cp3[3][288], di3[3][288];   // padded: idx = i+16, zeros outside [0,255]
  __shared__ float s_mean;
  const int dirc = blockIdx.x, dir = dirc / 3, c = dirc % 3;
  const int j = threadIdx.x;
  {
    const float4* p = (const float4*)((dir == 0 ? aspat : bspat) + c * HWn) + j;
    double acc = 0.0;
#pragma unroll
    for (int k2 = 0; k2 < 64; ++k2) {
      float4 v = p[k2 * 256];
      acc += (double)v.x + (double)v.y + (double)v.z + (double)v.w;
    }
    sm[j] = acc;
    __syncthreads();
    for (int s2 = 128; s2 > 0; s2 >>= 1) {
      if (j < s2) sm[j] += sm[j + s2];
      __syncthreads();
    }
    if (j == 0) s_mean = (float)(sm[0] * (1.0 / 65536.0));
    __syncthreads();
  }
  if (j < 3) {
    const int k = j;
    const float base = (dir == 0) ? alpha_base[c] : beta_base[c];
    const float coef = fminf(fmaxf(base + s_mean * ((float)k * DTf), EPSf), MAXCf);
    const float r = coef * (DTf * 0.5f);       // DX = 1
    for (int p = 0; p < 16; ++p) {
      cp3[k][p] = 0.f; di3[k][p] = 0.f;
      cp3[k][272 + p] = 0.f; di3[k][272 + p] = 0.f;
    }
    float b0 = 1.f + r + EPSf;                 // reference: b[0] + eps
    float cq = -r / b0, dq = 1.f / b0;
    cp3[k][16] = cq; di3[k][16] = dq;
    for (int i = 1; i < 256; ++i) {
      float b = (i == 255) ? (1.f + r) : (1.f + 2.f * r);
      float den = fmaxf(b + r * cq, EPSf);     // b - a*cp_prev, a = -r
      cq = -r / den; dq = 1.f / den;
      cp3[k][16 + i] = cq; di3[k][16 + i] = dq;
    }
  }
  float* tb = ws + ((dir == 0) ? WS_TAPX : WS_TAPY) + c * 5 * 256;
#pragma unroll
  for (int d = 0; d < 5; ++d) tb[d * 256 + j] = 0.f;    // OOB-source taps stay 0
  __syncthreads();

  float z[33];                                  // o = 0..32 <-> row i = j-16+o
#pragma unroll
  for (int o = 0; o < 33; ++o) z[o] = (o == 16) ? 1.f : 0.f;
#pragma unroll
  for (int k = 0; k < 3; ++k) {
    float dp = 0.f;
#pragma unroll
    for (int o = 0; o < 33; ++o) {              // forward: dp in place
      const int p = j + o;
      dp = fmaf(-cp3[k][p], dp, z[o] * di3[k][p]);
      z[o] = dp;
    }
    float x = 0.f;
#pragma unroll
    for (int o = 32; o >= 0; --o) {             // backward: x = dp - cp*x_next
      const int p = j + o;
      x = fmaf(-cp3[k][p], x, z[o]);
      z[o] = x;
    }
  }
  float scale = 1.f;
  if (dir == 1) {
    float dgc = coupling[c * 3 + c];
    scale = dgc * dgc * dgc;                    // diag applied after each step
  }
#pragma unroll
  for (int o = -2; o <= 2; ++o) {               // band +-2: d = 2 - o
    const int i = j + o;                        // output row; X[i][j]
    if ((unsigned)i < 256u) tb[(2 - o) * 256 + i] = z[o + 16] * scale;
  }
}

// ---- hot kernel: out = Y * u * X^T, 5-tap separable stencil ---------------
// Block = (plane, 64-row stripe): 68-row x 256-col LDS tile (69632 B ->
// 2 blocks/CU at (512,4); VGPR envelope proven R13/R14).
// LDS skew: quad q of a row at slot f(q)=q^(q>>3) (involution); DMA lane l
// -> linear slot l with pre-skewed source quad f(l) (rule #21).
// Stage 1 (barrier-free): wave wv owns rows {wv+8m} — DMAs them (1KB dense),
// per-wave vmcnt(0), x-convs lane-per-quad in place (+-1 quad halo within
// the wave; lockstep). Interior taps block-uniform s_load; edge lanes
// recompute cols 0-5/250-255 with true per-col taps (zero-padded table
// kills clamped-garbage sources — index-verified).
// ONE barrier. Stage 2: y-conv col-QUAD units, rolling float4 win[5],
// per-row taps via wave-uniform s_load, 1KB-dense float4 stores.
__global__ __launch_bounds__(512, 4) void conv5(
    const float* __restrict__ src, float* __restrict__ dst,
    const float* __restrict__ ws) {
  __shared__ float vt[68 * 256];               // 69632 B
  const int t = threadIdx.x;
  // XCD-bijective swizzle: 1536 = 8*192; same-plane stripes -> same XCD
  const int logical = (blockIdx.x & 7) * 192 + (blockIdx.x >> 3);
  const int plane = logical >> 2;
  const int st = logical & 3;
  const int c = plane % 3;
  const int h0 = st * 64;                      // core rows [h0, h0+64)
  const int a = (st == 0) ? 0 : (h0 - 2);
  const int b = (st == 3) ? 256 : (h0 + 66);
  const int Wv = b - a;                        // 66 edges, 68 interior
  const float* tpx = ws + WS_TAPX + c * 1280;
  const float* tpy = ws + WS_TAPY + c * 1280;
  const float* srcp = src + (size_t)plane * HWn;

  const int wv = t >> 6, l = t & 63;
  const int fl = l ^ (l >> 3);                 // involution skew

  // ---- DMA own rows: wave wv -> rows {wv + 8m} (1KB dense per load) ----
#pragma unroll
  for (int m = 0; m < 9; ++m) {
    const int rl = wv + 8 * m;
    if (rl < Wv) {
      const float* gp = srcp + (size_t)(a + rl) * 256 + (fl << 2);
      __builtin_amdgcn_global_load_lds(
          (const __attribute__((address_space(1))) void*)gp,
          (__attribute__((address_space(3))) void*)(vt + rl * 256), 16, 0, 0);
    }
  }
  float tx[5];                                  // interior x-taps (uniform -> s_load)
#pragma unroll
  for (int d = 0; d < 5; ++d) tx[d] = tpx[d * 256 + 128];
  asm volatile("s_waitcnt vmcnt(0)" ::: "memory");   // own rows only (per-wave)
  __builtin_amdgcn_sched_barrier(0);

  // ---- stage 1: x-conv own rows in place (lane-per-quad, 3 b128 reads) ----
#pragma unroll
  for (int m = 0; m < 9; ++m) {
    const int rl = wv + 8 * m;
    if (rl < Wv) {
      float* rowl = vt + rl * 256;
      float in_[12];                           // quads l-1..l+1 (clamped)
#pragma unroll
      for (int mm = 0; mm < 3; ++mm) {
        int q = l - 1 + mm;
        q = q < 0 ? 0 : (q > 63 ? 63 : q);
        const int sl = q ^ (q >> 3);
        *(float4*)&in_[4 * mm] = *(const float4*)(rowl + 4 * sl);
      }
      float acc[4];
#pragma unroll
      for (int e = 0; e < 4; ++e) acc[e] = tx[0] * in_[e + 2];
#pragma unroll
      for (int d = 1; d < 5; ++d)
#pragma unroll
        for (int e = 0; e < 4; ++e) acc[e] = fmaf(tx[d], in_[e + 2 + d], acc[e]);
      if (l < 2) {                             // true taps for cols 0..5
#pragma unroll
        for (int e = 0; e < 4; ++e) {
          const int col = 4 * l + e;
          if (col < 6) {
            float ac = 0.f;
#pragma unroll
            for (int d = 0; d < 5; ++d)
              ac = fmaf(tpx[d * 256 + col], in_[e + 2 + d], ac);
            acc[e] = ac;
          }
        }
      } else if (l >= 62) {                    // true taps for cols 250..255
#pragma unroll
        for (int e = 0; e < 4; ++e) {
          const int col = 4 * l + e;
          if (col >= 250) {
            float ac = 0.f;
#pragma unroll
            for (int d = 0; d < 5; ++d)
              ac = fmaf(tpx[d * 256 + col], in_[e + 2 + d], ac);
            acc[e] = ac;
          }
        }
      }
      *(float4*)(rowl + 4 * fl) =              // own quad l -> slot f(l)
          make_float4(acc[0], acc[1], acc[2], acc[3]);
    }
  }
  __syncthreads();                             // the ONE barrier

  // ---- stage 2: y-conv. unit = (col-quad q, 8-row chunk rc) ----
  const int q = t & 63, rc = t >> 6;           // rc wave-uniform
  const int wpos = (q ^ (q >> 3)) << 2;
  const int g0 = h0 + 8 * rc;
  float4 win[5];                               // rows g-2 .. g+2 of this quad
#pragma unroll
  for (int m = 0; m < 4; ++m) {
    int gg = g0 - 2 + m;
    gg = gg < a ? a : gg;                      // clamped read x zero tap
    win[m] = *(const float4*)(vt + (gg - a) * 256 + wpos);
  }
  float* dstp = dst + (size_t)plane * HWn + 4 * q;
#pragma unroll
  for (int rr = 0; rr < 8; ++rr) {
    const int g = g0 + rr;
    {
      int gg = g + 2;
      gg = gg > b - 1 ? b - 1 : gg;
      win[4] = *(const float4*)(vt + (gg - a) * 256 + wpos);
    }
    const int gu = __builtin_amdgcn_readfirstlane(g);
    float4 o;
    {
      const float ty = tpy[gu];                // wave-uniform -> s_load
      o.x = ty * win[0].x; o.y = ty * win[0].y;
      o.z = ty * win[0].z; o.w = ty * win[0].w;
    }
#pragma unroll
    for (int d = 1; d < 5; ++d) {
      const float ty = tpy[d * 256 + gu];
      o.x = fmaf(ty, win[d].x, o.x);
      o.y = fmaf(ty, win[d].y, o.y);
      o.z = fmaf(ty, win[d].z, o.z);
      o.w = fmaf(ty, win[d].w, o.w);
    }
    *(float4*)(dstp + (size_t)g * 256) = o;
#pragma unroll
    for (int m = 0; m < 4; ++m) win[m] = win[m + 1];
  }
}

extern "C" void kernel_launch(void* const* d_in, const int* in_sizes, int n_in,
                              void* d_out, int out_size, void* d_ws, size_t ws_size,
                              hipStream_t stream) {
  const float* u = (const float*)d_in[0];
  const float* alpha_base = (const float*)d_in[1];
  const float* beta_base = (const float*)d_in[2];
  const float* alpha_spatial = (const float*)d_in[3];
  const float* beta_spatial = (const float*)d_in[4];
  const float* coupling = (const float*)d_in[5];
  float* out = (float*)d_out;
  float* ws = (float*)d_ws;

  build_taps<<<6, 256, 0, stream>>>(alpha_base, beta_base,
                                    alpha_spatial, beta_spatial, coupling, ws);
  conv5<<<NPLANE * 4, 512, 0, stream>>>(u, out, ws);
}

// Round 21
// 78.502 us; speedup vs baseline: 3.0429x; 1.3379x over previous
//
#include <hip/hip_runtime.h>

// Problem constants (fixed by setup_inputs)
constexpr int Bn = 128, Cn = 3, Sn = 256;
constexpr int HWn = Sn * Sn;          // 65536
constexpr int NPLANE = Bn * Cn;       // 384
constexpr float DTf = 0.05f;
constexpr float EPSf = 1e-6f;
constexpr float MAXCf = 1.0f;

// ws float layout (band +-2 = 5 taps):
//   [128..3967]     tapx [3 c][5 d][256 i]   (zero for OOB sources)
//   [4096..7935]    tapy [3 c][5 d][256 i]   (dg^3 folded in; zero for OOB)
#define WS_TAPX 128
#define WS_TAPY 4096

// ---- build composed banded operator taps (+ fused spatial mean) ----------
// All T_k = I + r_k*L commute; thread j applies the three EXACT reference
// Thomas solves to basis vector e_j (rows [j-16,j+16] in regs).
// BAND +-2: tap(d) ~ (3r)^d with 3r~0.023 -> dropped-tap output error
// <= ~2e-8 << 2.15e-5 threshold (validated R20: absmax 3.8e-6).
__global__ void build_taps(const float* __restrict__ alpha_base,
                           const float* __restrict__ beta_base,
                           const float* __restrict__ aspat,
                           const float* __restrict__ bspat,
                           const float* __restrict__ coupling,
                           float* __restrict__ ws) {
  __shared__ double sm[256];
  __shared__ float cp3[3][288], di3[3][288];   // padded: idx = i+16, zeros outside [0,255]
  __shared__ float s_mean;
  const int dirc = blockIdx.x, dir = dirc / 3, c = dirc % 3;
  const int j = threadIdx.x;
  {
    const float4* p = (const float4*)((dir == 0 ? aspat : bspat) + c * HWn) + j;
    double acc = 0.0;
#pragma unroll
    for (int k2 = 0; k2 < 64; ++k2) {
      float4 v = p[k2 * 256];
      acc += (double)v.x + (double)v.y + (double)v.z + (double)v.w;
    }
    sm[j] = acc;
    __syncthreads();
    for (int s2 = 128; s2 > 0; s2 >>= 1) {
      if (j < s2) sm[j] += sm[j + s2];
      __syncthreads();
    }
    if (j == 0) s_mean = (float)(sm[0] * (1.0 / 65536.0));
    __syncthreads();
  }
  if (j < 3) {
    const int k = j;
    const float base = (dir == 0) ? alpha_base[c] : beta_base[c];
    const float coef = fminf(fmaxf(base + s_mean * ((float)k * DTf), EPSf), MAXCf);
    const float r = coef * (DTf * 0.5f);       // DX = 1
    for (int p = 0; p < 16; ++p) {
      cp3[k][p] = 0.f; di3[k][p] = 0.f;
      cp3[k][272 + p] = 0.f; di3[k][272 + p] = 0.f;
    }
    float b0 = 1.f + r + EPSf;                 // reference: b[0] + eps
    float cq = -r / b0, dq = 1.f / b0;
    cp3[k][16] = cq; di3[k][16] = dq;
    for (int i = 1; i < 256; ++i) {
      float b = (i == 255) ? (1.f + r) : (1.f + 2.f * r);
      float den = fmaxf(b + r * cq, EPSf);     // b - a*cp_prev, a = -r
      cq = -r / den; dq = 1.f / den;
      cp3[k][16 + i] = cq; di3[k][16 + i] = dq;
    }
  }
  float* tb = ws + ((dir == 0) ? WS_TAPX : WS_TAPY) + c * 5 * 256;
#pragma unroll
  for (int d = 0; d < 5; ++d) tb[d * 256 + j] = 0.f;    // OOB-source taps stay 0
  __syncthreads();

  float z[33];                                  // o = 0..32 <-> row i = j-16+o
#pragma unroll
  for (int o = 0; o < 33; ++o) z[o] = (o == 16) ? 1.f : 0.f;
#pragma unroll
  for (int k = 0; k < 3; ++k) {
    float dp = 0.f;
#pragma unroll
    for (int o = 0; o < 33; ++o) {              // forward: dp in place
      const int p = j + o;
      dp = fmaf(-cp3[k][p], dp, z[o] * di3[k][p]);
      z[o] = dp;
    }
    float x = 0.f;
#pragma unroll
    for (int o = 32; o >= 0; --o) {             // backward: x = dp - cp*x_next
      const int p = j + o;
      x = fmaf(-cp3[k][p], x, z[o]);
      z[o] = x;
    }
  }
  float scale = 1.f;
  if (dir == 1) {
    float dgc = coupling[c * 3 + c];
    scale = dgc * dgc * dgc;                    // diag applied after each step
  }
#pragma unroll
  for (int o = -2; o <= 2; ++o) {               // band +-2: d = 2 - o
    const int i = j + o;                        // output row; X[i][j]
    if ((unsigned)i < 256u) tb[(2 - o) * 256 + i] = z[o + 16] * scale;
  }
}

// ---- hot kernel: pure streaming separable 5-tap, sweep_y-style -----------
// Wave = (plane, 16-row stripe). Lane l owns float4 cols [4l,4l+4) of the
// full 256-col row (64 lanes x 4 = whole row -> NO cross-wave halo).
// Walk 20 rows (16 core + 2 halo/side): per row 1 dense 1KB load, 4 shfl
// (+-2 col window; lane-0/63 shuffle garbage killed by per-lane EXACT
// zero-padded tap vectors — no boundary branches), 20 FMA x-conv into a
// 5-slot rolling register window (literal indices), 20 FMA y-conv with
// row-uniform s_load taps (zero taps kill clamped halo rows), 1 dense store.
// Zero LDS, zero barriers. 6144 waves = 24/CU at (256,6).
__global__ __launch_bounds__(256, 6) void conv_stream(
    const float* __restrict__ src, float* __restrict__ dst,
    const float* __restrict__ ws) {
  const int t = threadIdx.x;
  // XCD-bijective swizzle: 1536 = 8*192; consecutive waves = same-plane
  // adjacent stripes -> halo rows L2-shared within an XCD.
  const int logical = (blockIdx.x & 7) * 192 + (blockIdx.x >> 3);
  const int wvu = __builtin_amdgcn_readfirstlane(t >> 6);
  const int W = logical * 4 + wvu;             // wave id, 0..6143
  const int plane = W >> 4;
  const int stripe = W & 15;
  const int c = plane % 3;
  const int l = t & 63;
  const float* tpx = ws + WS_TAPX + c * 1280;
  const float* tpy = ws + WS_TAPY + c * 1280;
  const float* sp = src + (size_t)plane * HWn + 4 * l;
  float* dp = dst + (size_t)plane * HWn + 4 * l;

  // per-lane EXACT x-taps for its 4 columns (zero-padded at boundaries)
  const float4 X0 = *(const float4*)(tpx + 0 * 256 + 4 * l);
  const float4 X1 = *(const float4*)(tpx + 1 * 256 + 4 * l);
  const float4 X2 = *(const float4*)(tpx + 2 * 256 + 4 * l);
  const float4 X3 = *(const float4*)(tpx + 3 * 256 + 4 * l);
  const float4 X4 = *(const float4*)(tpx + 4 * 256 + 4 * l);

  const int h0 = stripe * 16;
  float4 win[5];                                // literal-indexed only

#define XSTEP(H, WI)                                                         \
  {                                                                          \
    int hc = (H); hc = hc < 0 ? 0 : (hc > 255 ? 255 : hc);                   \
    float4 v = *(const float4*)(sp + (size_t)hc * 256);                      \
    float lz = __shfl_up(v.z, 1);                                            \
    float lw = __shfl_up(v.w, 1);                                            \
    float rx = __shfl_down(v.x, 1);                                          \
    float ry = __shfl_down(v.y, 1);                                          \
    float4 a;                                                                \
    a.x = X0.x * lz  + X1.x * lw  + X2.x * v.x + X3.x * v.y + X4.x * v.z;    \
    a.y = X0.y * lw  + X1.y * v.x + X2.y * v.y + X3.y * v.z + X4.y * v.w;    \
    a.z = X0.z * v.x + X1.z * v.y + X2.z * v.z + X3.z * v.w + X4.z * rx;     \
    a.w = X0.w * v.y + X1.w * v.z + X2.w * v.w + X3.w * rx  + X4.w * ry;     \
    win[WI] = a;                                                             \
  }
  // after XSTEP(h,WI): win[(WI+1+d)%5] = xc[h-4+d]; emit g=h-2 uses d=0..4
#define YEMIT(G, WI)                                                         \
  {                                                                          \
    const int g = (G);                                                       \
    const float t0 = tpy[0 * 256 + g];  /* wave-uniform -> s_load */         \
    const float t1 = tpy[1 * 256 + g];                                       \
    const float t2 = tpy[2 * 256 + g];                                       \
    const float t3 = tpy[3 * 256 + g];                                       \
    const float t4 = tpy[4 * 256 + g];                                       \
    const float4 s0 = win[((WI) + 1) % 5];                                   \
    const float4 s1 = win[((WI) + 2) % 5];                                   \
    const float4 s2 = win[((WI) + 3) % 5];                                   \
    const float4 s3 = win[((WI) + 4) % 5];                                   \
    const float4 s4 = win[(WI)];                                             \
    float4 o;                                                                \
    o.x = t0 * s0.x + t1 * s1.x + t2 * s2.x + t3 * s3.x + t4 * s4.x;         \
    o.y = t0 * s0.y + t1 * s1.y + t2 * s2.y + t3 * s3.y + t4 * s4.y;         \
    o.z = t0 * s0.z + t1 * s1.z + t2 * s2.z + t3 * s3.z + t4 * s4.z;         \
    o.w = t0 * s0.w + t1 * s1.w + t2 * s2.w + t3 * s3.w + t4 * s4.w;         \
    *(float4*)(dp + (size_t)g * 256) = o;                                    \
  }

  // prologue: 5 steps fill the window; first emit at g = h0
  XSTEP(h0 - 2, 0);
  XSTEP(h0 - 1, 1);
  XSTEP(h0 + 0, 2);
  XSTEP(h0 + 1, 3);
  XSTEP(h0 + 2, 4);
  YEMIT(h0 + 0, 4);
  // 3 chunks of 5: h = h0+3 .. h0+17, g = h0+1 .. h0+15
#pragma unroll
  for (int k = 0; k < 3; ++k) {
    const int hb = h0 + 3 + 5 * k;
    XSTEP(hb + 0, 0); YEMIT(hb - 2, 0);
    XSTEP(hb + 1, 1); YEMIT(hb - 1, 1);
    XSTEP(hb + 2, 2); YEMIT(hb + 0, 2);
    XSTEP(hb + 3, 3); YEMIT(hb + 1, 3);
    XSTEP(hb + 4, 4); YEMIT(hb + 2, 4);
  }
#undef XSTEP
#undef YEMIT
}

extern "C" void kernel_launch(void* const* d_in, const int* in_sizes, int n_in,
                              void* d_out, int out_size, void* d_ws, size_t ws_size,
                              hipStream_t stream) {
  const float* u = (const float*)d_in[0];
  const float* alpha_base = (const float*)d_in[1];
  const float* beta_base = (const float*)d_in[2];
  const float* alpha_spatial = (const float*)d_in[3];
  const float* beta_spatial = (const float*)d_in[4];
  const float* coupling = (const float*)d_in[5];
  float* out = (float*)d_out;
  float* ws = (float*)d_ws;

  build_taps<<<6, 256, 0, stream>>>(alpha_base, beta_base,
                                    alpha_spatial, beta_spatial, coupling, ws);
  conv_stream<<<NPLANE * 4, 256, 0, stream>>>(u, out, ws);
}

// Round 22
// 78.063 us; speedup vs baseline: 3.0600x; 1.0056x over previous
//
#include <hip/hip_runtime.h>

// Problem constants (fixed by setup_inputs)
constexpr int Bn = 128, Cn = 3, Sn = 256;
constexpr int HWn = Sn * Sn;          // 65536
constexpr int NPLANE = Bn * Cn;       // 384
constexpr float DTf = 0.05f;
constexpr float EPSf = 1e-6f;
constexpr float MAXCf = 1.0f;

// ws float layout (band +-2 = 5 taps):
//   [128..3967]     tapx [3 c][5 d][256 i]   (zero for OOB sources)
//   [4096..7935]    tapy [3 c][5 d][256 i]   (dg^3 folded in; zero for OOB)
#define WS_TAPX 128
#define WS_TAPY 4096

// ---- build composed banded operator taps (+ fused spatial mean) ----------
// All T_k = I + r_k*L commute; thread j applies the three EXACT reference
// Thomas solves to basis vector e_j (rows [j-16,j+16] in regs).
// BAND +-2: tap(d) ~ (3r)^d with 3r~0.023 -> dropped-tap output error
// <= ~2e-8 << 2.15e-5 threshold (validated R20/R21: absmax 3.8e-6).
__global__ void build_taps(const float* __restrict__ alpha_base,
                           const float* __restrict__ beta_base,
                           const float* __restrict__ aspat,
                           const float* __restrict__ bspat,
                           const float* __restrict__ coupling,
                           float* __restrict__ ws) {
  __shared__ double sm[256];
  __shared__ float cp3[3][288], di3[3][288];   // padded: idx = i+16, zeros outside [0,255]
  __shared__ float s_mean;
  const int dirc = blockIdx.x, dir = dirc / 3, c = dirc % 3;
  const int j = threadIdx.x;
  {
    const float4* p = (const float4*)((dir == 0 ? aspat : bspat) + c * HWn) + j;
    double acc = 0.0;
#pragma unroll
    for (int k2 = 0; k2 < 64; ++k2) {
      float4 v = p[k2 * 256];
      acc += (double)v.x + (double)v.y + (double)v.z + (double)v.w;
    }
    sm[j] = acc;
    __syncthreads();
    for (int s2 = 128; s2 > 0; s2 >>= 1) {
      if (j < s2) sm[j] += sm[j + s2];
      __syncthreads();
    }
    if (j == 0) s_mean = (float)(sm[0] * (1.0 / 65536.0));
    __syncthreads();
  }
  if (j < 3) {
    const int k = j;
    const float base = (dir == 0) ? alpha_base[c] : beta_base[c];
    const float coef = fminf(fmaxf(base + s_mean * ((float)k * DTf), EPSf), MAXCf);
    const float r = coef * (DTf * 0.5f);       // DX = 1
    for (int p = 0; p < 16; ++p) {
      cp3[k][p] = 0.f; di3[k][p] = 0.f;
      cp3[k][272 + p] = 0.f; di3[k][272 + p] = 0.f;
    }
    float b0 = 1.f + r + EPSf;                 // reference: b[0] + eps
    float cq = -r / b0, dq = 1.f / b0;
    cp3[k][16] = cq; di3[k][16] = dq;
    for (int i = 1; i < 256; ++i) {
      float b = (i == 255) ? (1.f + r) : (1.f + 2.f * r);
      float den = fmaxf(b + r * cq, EPSf);     // b - a*cp_prev, a = -r
      cq = -r / den; dq = 1.f / den;
      cp3[k][16 + i] = cq; di3[k][16 + i] = dq;
    }
  }
  float* tb = ws + ((dir == 0) ? WS_TAPX : WS_TAPY) + c * 5 * 256;
#pragma unroll
  for (int d = 0; d < 5; ++d) tb[d * 256 + j] = 0.f;    // OOB-source taps stay 0
  __syncthreads();

  float z[33];                                  // o = 0..32 <-> row i = j-16+o
#pragma unroll
  for (int o = 0; o < 33; ++o) z[o] = (o == 16) ? 1.f : 0.f;
#pragma unroll
  for (int k = 0; k < 3; ++k) {
    float dp = 0.f;
#pragma unroll
    for (int o = 0; o < 33; ++o) {              // forward: dp in place
      const int p = j + o;
      dp = fmaf(-cp3[k][p], dp, z[o] * di3[k][p]);
      z[o] = dp;
    }
    float x = 0.f;
#pragma unroll
    for (int o = 32; o >= 0; --o) {             // backward: x = dp - cp*x_next
      const int p = j + o;
      x = fmaf(-cp3[k][p], x, z[o]);
      z[o] = x;
    }
  }
  float scale = 1.f;
  if (dir == 1) {
    float dgc = coupling[c * 3 + c];
    scale = dgc * dgc * dgc;                    // diag applied after each step
  }
#pragma unroll
  for (int o = -2; o <= 2; ++o) {               // band +-2: d = 2 - o
    const int i = j + o;                        // output row; X[i][j]
    if ((unsigned)i < 256u) tb[(2 - o) * 256 + i] = z[o + 16] * scale;
  }
}

// ---- hot kernel: pure streaming separable 5-tap, grouped-load pipeline ----
// Wave = (plane, 16-row stripe). Lane l owns float4 cols [4l,4l+4) of the
// full 256-col row (no cross-wave halo). Per 5-emit chunk: issue 5
// INDEPENDENT dense 1KB loads first (v0..v4 — 5-deep memory pipeline per
// wave), then 5x {4 shfl, 20-FMA x-conv into rolling win[5], 20-FMA y-conv
// with row-uniform s_load taps, 1KB dense store}. Boundary handling purely
// via zero-padded per-lane tap vectors (shuffle garbage and clamped halo
// rows multiply zero taps — proven R21, absmax 3.8e-6).
// Zero LDS, zero barriers. (256,6): VGPR cap 85, 24 waves/CU.
__global__ __launch_bounds__(256, 6) void conv_stream(
    const float* __restrict__ src, float* __restrict__ dst,
    const float* __restrict__ ws) {
  const int t = threadIdx.x;
  // XCD-bijective swizzle: 1536 = 8*192; consecutive waves = same-plane
  // adjacent stripes -> halo rows L2-shared within an XCD.
  const int logical = (blockIdx.x & 7) * 192 + (blockIdx.x >> 3);
  const int wvu = __builtin_amdgcn_readfirstlane(t >> 6);
  const int W = logical * 4 + wvu;             // wave id, 0..6143
  const int plane = W >> 4;
  const int stripe = W & 15;
  const int c = plane % 3;
  const int l = t & 63;
  const float* tpx = ws + WS_TAPX + c * 1280;
  const float* tpy = ws + WS_TAPY + c * 1280;
  const float* sp = src + (size_t)plane * HWn + 4 * l;
  float* dp = dst + (size_t)plane * HWn + 4 * l;

  // per-lane EXACT x-taps for its 4 columns (zero-padded at boundaries)
  const float4 X0 = *(const float4*)(tpx + 0 * 256 + 4 * l);
  const float4 X1 = *(const float4*)(tpx + 1 * 256 + 4 * l);
  const float4 X2 = *(const float4*)(tpx + 2 * 256 + 4 * l);
  const float4 X3 = *(const float4*)(tpx + 3 * 256 + 4 * l);
  const float4 X4 = *(const float4*)(tpx + 4 * 256 + 4 * l);

  const int h0 = stripe * 16;
  float4 win[5];                                // literal-indexed only
  float4 v0, v1, v2, v3, v4;                    // grouped-load staging

#define XLOAD(H, VR)                                                         \
  {                                                                          \
    int hc = (H); hc = hc < 0 ? 0 : (hc > 255 ? 255 : hc);                   \
    VR = *(const float4*)(sp + (size_t)hc * 256);                            \
  }
#define XCOMP(VR, WI)                                                        \
  {                                                                          \
    float lz = __shfl_up(VR.z, 1);                                           \
    float lw = __shfl_up(VR.w, 1);                                           \
    float rx = __shfl_down(VR.x, 1);                                         \
    float ry = __shfl_down(VR.y, 1);                                         \
    float4 a;                                                                \
    a.x = X0.x * lz   + X1.x * lw   + X2.x * VR.x + X3.x * VR.y + X4.x * VR.z;\
    a.y = X0.y * lw   + X1.y * VR.x + X2.y * VR.y + X3.y * VR.z + X4.y * VR.w;\
    a.z = X0.z * VR.x + X1.z * VR.y + X2.z * VR.z + X3.z * VR.w + X4.z * rx; \
    a.w = X0.w * VR.y + X1.w * VR.z + X2.w * VR.w + X3.w * rx   + X4.w * ry; \
    win[WI] = a;                                                             \
  }
#define YEMIT(G, WI)                                                         \
  {                                                                          \
    const int g = (G);                                                       \
    const float t0 = tpy[0 * 256 + g];  /* wave-uniform -> s_load */         \
    const float t1 = tpy[1 * 256 + g];                                       \
    const float t2 = tpy[2 * 256 + g];                                       \
    const float t3 = tpy[3 * 256 + g];                                       \
    const float t4 = tpy[4 * 256 + g];                                       \
    const float4 s0 = win[((WI) + 1) % 5];                                   \
    const float4 s1 = win[((WI) + 2) % 5];                                   \
    const float4 s2 = win[((WI) + 3) % 5];                                   \
    const float4 s3 = win[((WI) + 4) % 5];                                   \
    const float4 s4 = win[(WI)];                                             \
    float4 o;                                                                \
    o.x = t0 * s0.x + t1 * s1.x + t2 * s2.x + t3 * s3.x + t4 * s4.x;         \
    o.y = t0 * s0.y + t1 * s1.y + t2 * s2.y + t3 * s3.y + t4 * s4.y;         \
    o.z = t0 * s0.z + t1 * s1.z + t2 * s2.z + t3 * s3.z + t4 * s4.z;         \
    o.w = t0 * s0.w + t1 * s1.w + t2 * s2.w + t3 * s3.w + t4 * s4.w;         \
    *(float4*)(dp + (size_t)g * 256) = o;                                    \
  }

  // prologue: 5 grouped loads, then 5 x-convs fill the window; emit g = h0
  XLOAD(h0 - 2, v0); XLOAD(h0 - 1, v1); XLOAD(h0 + 0, v2);
  XLOAD(h0 + 1, v3); XLOAD(h0 + 2, v4);
  XCOMP(v0, 0); XCOMP(v1, 1); XCOMP(v2, 2); XCOMP(v3, 3); XCOMP(v4, 4);
  YEMIT(h0 + 0, 4);
  // 3 chunks of 5: loads first (5 in flight), then compute+emit
#pragma unroll
  for (int k = 0; k < 3; ++k) {
    const int hb = h0 + 3 + 5 * k;
    XLOAD(hb + 0, v0); XLOAD(hb + 1, v1); XLOAD(hb + 2, v2);
    XLOAD(hb + 3, v3); XLOAD(hb + 4, v4);
    XCOMP(v0, 0); YEMIT(hb - 2, 0);
    XCOMP(v1, 1); YEMIT(hb - 1, 1);
    XCOMP(v2, 2); YEMIT(hb + 0, 2);
    XCOMP(v3, 3); YEMIT(hb + 1, 3);
    XCOMP(v4, 4); YEMIT(hb + 2, 4);
  }
#undef XLOAD
#undef XCOMP
#undef YEMIT
}

extern "C" void kernel_launch(void* const* d_in, const int* in_sizes, int n_in,
                              void* d_out, int out_size, void* d_ws, size_t ws_size,
                              hipStream_t stream) {
  const float* u = (const float*)d_in[0];
  const float* alpha_base = (const float*)d_in[1];
  const float* beta_base = (const float*)d_in[2];
  const float* alpha_spatial = (const float*)d_in[3];
  const float* beta_spatial = (const float*)d_in[4];
  const float* coupling = (const float*)d_in[5];
  float* out = (float*)d_out;
  float* ws = (float*)d_ws;

  build_taps<<<6, 256, 0, stream>>>(alpha_base, beta_base,
                                    alpha_spatial, beta_spatial, coupling, ws);
  conv_stream<<<NPLANE * 4, 256, 0, stream>>>(u, out, ws);
}